// Round 7
// baseline (1454.481 us; speedup 1.0000x reference)
//
#include <hip/hip_runtime.h>

// GraphTransformerModel: 2-layer graph attention network.
// CSR build -> bf16 MFMA GEMMs (single-stage 128KB-LDS full-N tiles, swizzled)
// -> attn0 (quarter-wave/edge) -> gres0+LN -> 4x {qkv1 GEMM -> attn1} -> gres1.
// q/k/v live in fused [N][384] bf16 buffers; all accumulation f32.
// Peak workspace ~186 MB.

typedef unsigned short u16;
typedef __attribute__((ext_vector_type(8))) unsigned short ushort8;
typedef __attribute__((ext_vector_type(8))) short short8v;   // 8 bf16 (4 VGPRs)
typedef __attribute__((ext_vector_type(4))) float f32x4;

__device__ __forceinline__ float bf2f(unsigned short u) {
    return __uint_as_float(((unsigned)u) << 16);
}
__device__ __forceinline__ unsigned short f2bf(float f) {
    unsigned u = __float_as_uint(f);
    unsigned r = 0x7fffu + ((u >> 16) & 1u);   // round-to-nearest-even
    return (unsigned short)((u + r) >> 16);
}

// async global->LDS, 16B per lane; dest is wave-uniform base + lane*16 (HW).
__device__ __forceinline__ void gload16(const void* gp, const void* lp) {
    __builtin_amdgcn_global_load_lds(
        (const __attribute__((address_space(1))) unsigned*)(uintptr_t)gp,
        (__attribute__((address_space(3))) unsigned*)(unsigned)(uintptr_t)lp,
        16, 0, 0);
}

// ---------------- fused weight prep: all transposed bf16 weights in one kernel ----------------
// arena (u16): [0)=inWt[128][256]  [32768)=qkv0t[384][128]  [81920)=r0t[128][128]
//              [98304)=qkv1t[4][384][128]  [294912)=r1t[64][128]  total 303104
__global__ void prep_k(const float* __restrict__ inW,
                       const float* __restrict__ q0W, const float* __restrict__ k0W,
                       const float* __restrict__ v0W, const float* __restrict__ r0W,
                       const float* __restrict__ q1W, const float* __restrict__ k1W,
                       const float* __restrict__ v1W, const float* __restrict__ r1W,
                       u16* __restrict__ arena) {
    int i = blockIdx.x * 256 + threadIdx.x;
    if (i >= 303104) return;
    float val;
    if (i < 32768) {                       // inWt[n][k] = inW[k][n], K=256, N=128
        int n = i >> 8, k = i & 255;
        val = inW[k * 128 + n];
    } else if (i < 81920) {                // qkv0t
        int j = i - 32768;
        int r = j >> 7, kk = j & 127;
        int sec = r >> 7, c = r & 127;
        const float* s = (sec == 0) ? q0W : (sec == 1) ? k0W : v0W;
        val = s[kk * 128 + c];
    } else if (i < 98304) {                // r0t
        int j = i - 81920;
        int r = j >> 7, kk = j & 127;
        val = r0W[kk * 128 + r];
    } else if (i < 294912) {               // qkv1t[p][384][128]
        int j = i - 98304;
        int row = j >> 7, kk = j & 127;
        int p = row / 384, rr = row - p * 384;
        int sec = rr >> 7, c = p * 128 + (rr & 127);
        const float* s = (sec == 0) ? q1W : (sec == 1) ? k1W : v1W;
        val = s[kk * 512 + c];
    } else {                               // r1t[64][128]
        int j = i - 294912;
        int n = j >> 7, kk = j & 127;
        val = r1W[kk * 64 + n];
    }
    arena[i] = f2bf(val);
}

// fused biases: qkv0b[384] then qkv1b[4*384]
__global__ void bias_k(const float* __restrict__ q0b, const float* __restrict__ k0b,
                       const float* __restrict__ v0b,
                       const float* __restrict__ q1b, const float* __restrict__ k1b,
                       const float* __restrict__ v1b, float* __restrict__ out) {
    int i = blockIdx.x * 256 + threadIdx.x;
    if (i >= 1920) return;
    if (i < 384) {
        int sec = i >> 7, c = i & 127;
        out[i] = (sec == 0) ? q0b[c] : (sec == 1) ? k0b[c] : v0b[c];
    } else {
        int j = i - 384;
        int p = j / 384, rr = j - p * 384;
        int sec = rr >> 7, c = p * 128 + (rr & 127);
        out[i] = (sec == 0) ? q1b[c] : (sec == 1) ? k1b[c] : v1b[c];
    }
}

// ---------------- f32 -> bf16 convert (8 elems/thread) ----------------
__global__ void cvt_k(const float* __restrict__ in, u16* __restrict__ out, int n8) {
    int i = blockIdx.x * 256 + threadIdx.x;
    if (i >= n8) return;
    float4 a = *(const float4*)(in + (size_t)i * 8);
    float4 b = *(const float4*)(in + (size_t)i * 8 + 4);
    ushort8 o = {f2bf(a.x), f2bf(a.y), f2bf(a.z), f2bf(a.w),
                 f2bf(b.x), f2bf(b.y), f2bf(b.z), f2bf(b.w)};
    *(ushort8*)(out + (size_t)i * 8) = o;
}

// ---------------- MFMA GEMM v4: full-N single-stage tiles ----------------
// One block = 128 A-rows x full N. LDS holds the A tile (128 x K) AND the
// whole B panel (N x K) -- staged once via global_load_lds (pre-swizzled
// source, XOR on read), one barrier, then N/128 register passes.
// 256 thr = 4 waves (2x2 of 64x64). N % 128 == 0.
template <bool OUTBF16, int K, int N>
__global__ __launch_bounds__(256) void mgemm4(const u16* __restrict__ A,
                                              const u16* __restrict__ Bt,
                                              const float* __restrict__ bias,
                                              void* __restrict__ C, int M, int ldc) {
    constexpr int CPR = K / 8;            // 16B chunks per row
    constexpr int RPS = 64 / CPR;         // rows per 1KB wave-seg
    constexpr int ROWS = 128 + N;         // A rows, then B rows
    constexpr int SEGS = ROWS / RPS;
    constexpr int ASEG = 128 / RPS;       // segs holding A
    __shared__ __align__(16) u16 lds[ROWS * K];   // up to 128 KB
    const int bm = blockIdx.x * 128;
    const int t = threadIdx.x, lane = t & 63, wid = t >> 6;
    const int wm = (wid >> 1) * 64, wn0 = (wid & 1) * 64;
    const int lrow = lane / CPR, lchunk = lane % CPR;
    // ---- stage A tile + whole B panel, linear LDS, swizzled source ----
    for (int sg = 0; sg < SEGS; sg += 4) {
        int seg = sg + wid;                       // wave-uniform
        int row = seg * RPS + lrow;
        int lc = (lchunk ^ (row & 7)) * 8;        // pre-swizzled source col
        const u16* g;
        if (seg < ASEG) {
            int gr = bm + row; if (gr >= M) gr = 0;    // clamped; epilogue guards
            g = A + (size_t)gr * K + lc;
        } else {
            g = Bt + (size_t)(row - 128) * K + lc;
        }
        gload16(g, (const char*)lds + seg * 1024);
    }
    __syncthreads();   // drains vmcnt before LDS reads
    // ---- compute N/128 col-tiles from LDS ----
    for (int nit = 0; nit < N / 128; ++nit) {
        const int bn = nit * 128;
        f32x4 acc[4][4] = {};
#pragma unroll
        for (int ks = 0; ks < K / 32; ++ks) {
            const int jx = ks * 4 + (lane >> 4);   // logical 16B chunk index
            short8v af[4], bfr[4];
#pragma unroll
            for (int i = 0; i < 4; ++i) {
                int ra = wm + i * 16 + (lane & 15);
                af[i] = *(const short8v*)((const char*)lds + (size_t)ra * (2 * K) +
                                          ((jx ^ (ra & 7)) << 4));
                int rb = 128 + bn + wn0 + i * 16 + (lane & 15);
                bfr[i] = *(const short8v*)((const char*)lds + (size_t)rb * (2 * K) +
                                           ((jx ^ (rb & 7)) << 4));
            }
#pragma unroll
            for (int mi = 0; mi < 4; ++mi)
#pragma unroll
                for (int ni = 0; ni < 4; ++ni)
                    acc[mi][ni] = __builtin_amdgcn_mfma_f32_16x16x32_bf16(
                        af[mi], bfr[ni], acc[mi][ni], 0, 0, 0);
        }
        // epilogue: C/D frag layout col=lane&15, row=(lane>>4)*4+j
#pragma unroll
        for (int ni = 0; ni < 4; ++ni) {
            int ccol = bn + wn0 + ni * 16 + (lane & 15);
            float bs = bias[ccol];
#pragma unroll
            for (int mi = 0; mi < 4; ++mi) {
#pragma unroll
                for (int j = 0; j < 4; ++j) {
                    int crow = bm + wm + mi * 16 + (lane >> 4) * 4 + j;
                    if (crow >= M) continue;
                    float val = acc[mi][ni][j] + bs;
                    if (OUTBF16) ((u16*)C)[(size_t)crow * ldc + ccol] = f2bf(val);
                    else         ((float*)C)[(size_t)crow * ldc + ccol] = val;
                }
            }
        }
    }
}

// ---------------- MFMA GEMM v3 (kept for r1, N=64): 128x128, BK=64 chunks ----------
template <bool OUTBF16, int K>
__global__ __launch_bounds__(256) void mgemm3(const u16* __restrict__ A,
                                              const u16* __restrict__ Bt,
                                              const float* __restrict__ bias,
                                              void* __restrict__ C,
                                              int M, int Nvalid, int ldc) {
    __shared__ __align__(16) u16 As[128 * 64];
    __shared__ __align__(16) u16 Bs[128 * 64];
    const int bm = blockIdx.x * 128;
    const int bn = blockIdx.y * 128;
    const int t = threadIdx.x, lane = t & 63, wid = t >> 6;
    const int wm = (wid >> 1) * 64, wn = (wid & 1) * 64;
    const int jlog = ((lane & 7) ^ (lane >> 3)) * 8;
    f32x4 acc[4][4] = {};
    for (int k0 = 0; k0 < K; k0 += 64) {
#pragma unroll
        for (int c2 = 0; c2 < 4; ++c2) {
            int seg = c2 * 4 + wid;
            int row = seg * 8 + (lane >> 3);
            int ga = bm + row; if (ga >= M) ga = 0;
            gload16(A + (size_t)ga * K + k0 + jlog, (const char*)As + seg * 1024);
            int gb = bn + row; if (gb >= Nvalid) gb = 0;
            gload16(Bt + (size_t)gb * K + k0 + jlog, (const char*)Bs + seg * 1024);
        }
        __syncthreads();
#pragma unroll
        for (int ks = 0; ks < 2; ++ks) {
            const int jx = ks * 4 + (lane >> 4);
            short8v af[4], bfr[4];
#pragma unroll
            for (int i = 0; i < 4; ++i) {
                int ra = wm + i * 16 + (lane & 15);
                af[i] = *(const short8v*)((const char*)As + ra * 128 + ((jx ^ (ra & 7)) << 4));
                int rb = wn + i * 16 + (lane & 15);
                bfr[i] = *(const short8v*)((const char*)Bs + rb * 128 + ((jx ^ (rb & 7)) << 4));
            }
#pragma unroll
            for (int mi = 0; mi < 4; ++mi)
#pragma unroll
                for (int ni = 0; ni < 4; ++ni)
                    acc[mi][ni] = __builtin_amdgcn_mfma_f32_16x16x32_bf16(
                        af[mi], bfr[ni], acc[mi][ni], 0, 0, 0);
        }
        if (k0 + 64 < K) __syncthreads();
    }
#pragma unroll
    for (int ni = 0; ni < 4; ++ni) {
        int ccol = bn + wn + ni * 16 + (lane & 15);
        if (ccol >= Nvalid) continue;
        float bs = bias[ccol];
#pragma unroll
        for (int mi = 0; mi < 4; ++mi) {
#pragma unroll
            for (int j = 0; j < 4; ++j) {
                int crow = bm + wm + mi * 16 + (lane >> 4) * 4 + j;
                if (crow >= M) continue;
                float val = acc[mi][ni][j] + bs;
                if (OUTBF16) ((u16*)C)[(size_t)crow * ldc + ccol] = f2bf(val);
                else         ((float*)C)[(size_t)crow * ldc + ccol] = val;
            }
        }
    }
}

// ---------------- CSR build ----------------
__global__ void zero2_k(int* __restrict__ a, int* __restrict__ b, int n) {
    int i = blockIdx.x * 256 + threadIdx.x;
    if (i < n) { a[i] = 0; b[i] = 0; }
}

__global__ void hist_k(const int* __restrict__ dst, int* __restrict__ cnt, int E) {
    int i = blockIdx.x * 256 + threadIdx.x;
    if (i < E) atomicAdd(&cnt[dst[i]], 1);
}

__global__ void blocksum_k(const int* __restrict__ cnt, int* __restrict__ bsum, int n) {
    __shared__ int sd[256];
    int i = blockIdx.x * 256 + threadIdx.x;
    sd[threadIdx.x] = (i < n) ? cnt[i] : 0;
    __syncthreads();
    for (int off = 128; off > 0; off >>= 1) {
        if (threadIdx.x < off) sd[threadIdx.x] += sd[threadIdx.x + off];
        __syncthreads();
    }
    if (threadIdx.x == 0) bsum[blockIdx.x] = sd[0];
}

__global__ void scanb_k(int* bsum, int nb) {
    __shared__ int tmp[512];
    int t = threadIdx.x;
    tmp[t] = (t < nb) ? bsum[t] : 0;
    __syncthreads();
    for (int off = 1; off < 512; off <<= 1) {
        int v = (t >= off) ? tmp[t - off] : 0;
        __syncthreads();
        tmp[t] += v;
        __syncthreads();
    }
    if (t < nb) bsum[t] = (t ? tmp[t - 1] : 0);
}

__global__ void scanc_k(const int* __restrict__ cnt, const int* __restrict__ bsum,
                        int* __restrict__ row_off, int n, int E) {
    __shared__ int tmp[256];
    int b = blockIdx.x, t = threadIdx.x;
    int i = b * 256 + t;
    int own = (i < n) ? cnt[i] : 0;
    tmp[t] = own;
    __syncthreads();
    for (int off = 1; off < 256; off <<= 1) {
        int v = (t >= off) ? tmp[t - off] : 0;
        __syncthreads();
        tmp[t] += v;
        __syncthreads();
    }
    if (i < n) row_off[i] = bsum[b] + tmp[t] - own;
    if (b == 0 && t == 0) row_off[n] = E;
}

__global__ void scatter_k(const int* __restrict__ src, const int* __restrict__ dst,
                          const int* __restrict__ row_off, int* __restrict__ cur,
                          int* __restrict__ csr_src, int E) {
    int i = blockIdx.x * 256 + threadIdx.x;
    if (i < E) {
        int d = dst[i];
        int pos = row_off[d] + atomicAdd(&cur[d], 1);
        csr_src[pos] = src[i];
    }
}

// ---------------- attention layer 0: 8 heads x d=16, F=128, concat ----------------
// quarter-wave (16 lanes) per edge, 8 feats/lane via ushort8; head = 2 lanes.
// qkv fused [N][384]: q+0, k+128, v+256. 8 edges per loop iteration.
__global__ __launch_bounds__(256) void attn0_k(const u16* __restrict__ qkv,
                                               const int* __restrict__ row_off,
                                               const int* __restrict__ csr,
                                               float* __restrict__ out, int n) {
    int w = (blockIdx.x * 256 + threadIdx.x) >> 6;
    int lane = threadIdx.x & 63;
    if (w >= n) return;
    int beg = row_off[w], end = row_off[w + 1];
    const int qd = lane >> 4, fl = lane & 15;
    float kr[8];
    {
        ushort8 k8 = *(const ushort8*)(qkv + (size_t)w * 384 + 128 + fl * 8);
#pragma unroll
        for (int j = 0; j < 8; ++j) kr[j] = bf2f(k8[j]) * 0.25f;   // fold 1/sqrt(16)
    }
    float den = 0.f, num[8] = {};
    for (int e = beg; e < end; e += 8) {
        int ei0 = e + qd, ei1 = e + 4 + qd;
        bool va = ei0 < end, vb = ei1 < end;
        int s0 = csr[va ? ei0 : beg];
        int s1 = csr[vb ? ei1 : beg];
        const u16* r0 = qkv + (size_t)s0 * 384 + fl * 8;
        const u16* r1 = qkv + (size_t)s1 * 384 + fl * 8;
        ushort8 q80 = *(const ushort8*)r0;
        ushort8 v80 = *(const ushort8*)(r0 + 256);
        ushort8 q81 = *(const ushort8*)r1;
        ushort8 v81 = *(const ushort8*)(r1 + 256);
        float p0 = 0.f, p1 = 0.f;
#pragma unroll
        for (int j = 0; j < 8; ++j) {
            p0 = fmaf(bf2f(q80[j]), kr[j], p0);
            p1 = fmaf(bf2f(q81[j]), kr[j], p1);
        }
        p0 += __shfl_xor(p0, 1);          // head = 2 lanes (16 dims)
        p1 += __shfl_xor(p1, 1);
        float w0 = va ? __expf(p0) : 0.f;
        float w1 = vb ? __expf(p1) : 0.f;
        den += w0 + w1;
#pragma unroll
        for (int j = 0; j < 8; ++j) {
            num[j] = fmaf(w0, bf2f(v80[j]), num[j]);
            num[j] = fmaf(w1, bf2f(v81[j]), num[j]);
        }
    }
    den += __shfl_xor(den, 16); den += __shfl_xor(den, 32);
#pragma unroll
    for (int j = 0; j < 8; ++j) {
        num[j] += __shfl_xor(num[j], 16);
        num[j] += __shfl_xor(num[j], 32);
    }
    if (qd == 0) {
        float inv = (end > beg) ? 1.f / den : 0.f;
        float* op = out + ((size_t)w << 7) + fl * 8;
        *(float4*)op = make_float4(num[0] * inv, num[1] * inv, num[2] * inv, num[3] * inv);
        *(float4*)(op + 4) = make_float4(num[4] * inv, num[5] * inv, num[6] * inv, num[7] * inv);
    }
}

// ---------------- attention layer 1 (one 2-head pass): d=64, accumulate mean ----------------
// quarter-wave per edge; head = 8 lanes (64 dims); slice [N][384]: q+0,k+128,v+256.
template <bool FIRST>
__global__ __launch_bounds__(256) void attn1_k(const u16* __restrict__ qkv,
                                               const int* __restrict__ row_off,
                                               const int* __restrict__ csr,
                                               float* __restrict__ out, int n) {
    int w = (blockIdx.x * 256 + threadIdx.x) >> 6;
    int lane = threadIdx.x & 63;
    if (w >= n) return;
    int beg = row_off[w], end = row_off[w + 1];
    const int qd = lane >> 4, fl = lane & 15;
    float kr[8];
    {
        ushort8 k8 = *(const ushort8*)(qkv + (size_t)w * 384 + 128 + fl * 8);
#pragma unroll
        for (int j = 0; j < 8; ++j) kr[j] = bf2f(k8[j]) * 0.125f;   // fold 1/sqrt(64)
    }
    float den = 0.f, num[8] = {};
    for (int e = beg; e < end; e += 8) {
        int ei0 = e + qd, ei1 = e + 4 + qd;
        bool va = ei0 < end, vb = ei1 < end;
        int s0 = csr[va ? ei0 : beg];
        int s1 = csr[vb ? ei1 : beg];
        const u16* r0 = qkv + (size_t)s0 * 384 + fl * 8;
        const u16* r1 = qkv + (size_t)s1 * 384 + fl * 8;
        ushort8 q80 = *(const ushort8*)r0;
        ushort8 v80 = *(const ushort8*)(r0 + 256);
        ushort8 q81 = *(const ushort8*)r1;
        ushort8 v81 = *(const ushort8*)(r1 + 256);
        float p0 = 0.f, p1 = 0.f;
#pragma unroll
        for (int j = 0; j < 8; ++j) {
            p0 = fmaf(bf2f(q80[j]), kr[j], p0);
            p1 = fmaf(bf2f(q81[j]), kr[j], p1);
        }
        p0 += __shfl_xor(p0, 1); p0 += __shfl_xor(p0, 2); p0 += __shfl_xor(p0, 4);
        p1 += __shfl_xor(p1, 1); p1 += __shfl_xor(p1, 2); p1 += __shfl_xor(p1, 4);
        float w0 = va ? __expf(p0) : 0.f;
        float w1 = vb ? __expf(p1) : 0.f;
        den += w0 + w1;
#pragma unroll
        for (int j = 0; j < 8; ++j) {
            num[j] = fmaf(w0, bf2f(v80[j]), num[j]);
            num[j] = fmaf(w1, bf2f(v81[j]), num[j]);
        }
    }
    den += __shfl_xor(den, 16); den += __shfl_xor(den, 32);
#pragma unroll
    for (int j = 0; j < 8; ++j) {
        num[j] += __shfl_xor(num[j], 16);
        num[j] += __shfl_xor(num[j], 32);
    }
    float inv = (end > beg) ? 1.f / den : 0.f;   // per-head den (own lane group)
    float o[8];
#pragma unroll
    for (int j = 0; j < 8; ++j) {
        o[j] = num[j] * inv;
        o[j] += __shfl_xor(o[j], 8);             // combine the pass's 2 heads
    }
    if (lane < 8) {
        float* op = out + ((size_t)w << 6) + fl * 8;
        if (FIRST) {
            *(float4*)op = make_float4(o[0] * 0.125f, o[1] * 0.125f, o[2] * 0.125f, o[3] * 0.125f);
            *(float4*)(op + 4) = make_float4(o[4] * 0.125f, o[5] * 0.125f, o[6] * 0.125f, o[7] * 0.125f);
        } else {
            float4 t0 = *(float4*)op, t1 = *(float4*)(op + 4);
            t0.x += o[0] * 0.125f; t0.y += o[1] * 0.125f;
            t0.z += o[2] * 0.125f; t0.w += o[3] * 0.125f;
            t1.x += o[4] * 0.125f; t1.y += o[5] * 0.125f;
            t1.z += o[6] * 0.125f; t1.w += o[7] * 0.125f;
            *(float4*)op = t0; *(float4*)(op + 4) = t1;
        }
    }
}

// ---------------- gated residual + LN + relu (layer 0), bf16 h1 out ----------------
__global__ __launch_bounds__(256) void gres0_k(const float* __restrict__ x, const float* __restrict__ res,
                                               const float* __restrict__ gw,
                                               const float* __restrict__ lng, const float* __restrict__ lnb,
                                               u16* __restrict__ h1, int n) {
    int w = (blockIdx.x * 256 + threadIdx.x) >> 6;
    int lane = threadIdx.x & 63;
    if (w >= n) return;
    size_t base = (size_t)w * 128;
    float x1 = x[base + lane], x2 = x[base + lane + 64];
    float r1 = res[base + lane], r2 = res[base + lane + 64];
    float ca1 = gw[lane] + gw[256 + lane];
    float ca2 = gw[lane + 64] + gw[256 + lane + 64];
    float cr1 = gw[128 + lane] - gw[256 + lane];
    float cr2 = gw[128 + lane + 64] - gw[256 + lane + 64];
    float dot = x1 * ca1 + x2 * ca2 + r1 * cr1 + r2 * cr2;
#pragma unroll
    for (int off = 1; off < 64; off <<= 1) dot += __shfl_xor(dot, off);
    float g = 1.f / (1.f + __expf(-dot));
    float o1 = x1 * g + r1 * (1.f - g);
    float o2 = x2 * g + r2 * (1.f - g);
    float s = o1 + o2;
#pragma unroll
    for (int off = 1; off < 64; off <<= 1) s += __shfl_xor(s, off);
    float mu = s * (1.f / 128.f);
    float d1 = o1 - mu, d2 = o2 - mu;
    float vs = d1 * d1 + d2 * d2;
#pragma unroll
    for (int off = 1; off < 64; off <<= 1) vs += __shfl_xor(vs, off);
    float rstd = rsqrtf(vs * (1.f / 128.f) + 1e-5f);
    float y1 = d1 * rstd * lng[lane] + lnb[lane];
    float y2 = d2 * rstd * lng[lane + 64] + lnb[lane + 64];
    h1[base + lane] = f2bf(fmaxf(y1, 0.f));
    h1[base + lane + 64] = f2bf(fmaxf(y2, 0.f));
}

// ---------------- gated residual only (layer 1, d=64) ----------------
__global__ __launch_bounds__(256) void gres1_k(const float* __restrict__ x, const float* __restrict__ res,
                                               const float* __restrict__ gw,
                                               float* __restrict__ out, int n) {
    int w = (blockIdx.x * 256 + threadIdx.x) >> 6;
    int lane = threadIdx.x & 63;
    if (w >= n) return;
    size_t base = (size_t)w * 64;
    float xv = x[base + lane];
    float rv = res[base + lane];
    float ca = gw[lane] + gw[128 + lane];
    float cr = gw[64 + lane] - gw[128 + lane];
    float dot = xv * ca + rv * cr;
#pragma unroll
    for (int off = 1; off < 64; off <<= 1) dot += __shfl_xor(dot, off);
    float g = 1.f / (1.f + __expf(-dot));
    out[base + lane] = xv * g + rv * (1.f - g);
}

extern "C" void kernel_launch(void* const* d_in, const int* in_sizes, int n_in,
                              void* d_out, int out_size, void* d_ws, size_t ws_size,
                              hipStream_t stream) {
    const float* x    = (const float*)d_in[0];
    const int*   src  = (const int*)d_in[1];
    const int*   dst  = (const int*)d_in[2];
    const float* in_W = (const float*)d_in[3];
    const float* in_b = (const float*)d_in[4];
    const float* q0W = (const float*)d_in[5];  const float* q0b = (const float*)d_in[6];
    const float* k0W = (const float*)d_in[7];  const float* k0b = (const float*)d_in[8];
    const float* v0W = (const float*)d_in[9];  const float* v0b = (const float*)d_in[10];
    const float* r0W = (const float*)d_in[11]; const float* r0b = (const float*)d_in[12];
    const float* g0W = (const float*)d_in[13];
    const float* ln0g = (const float*)d_in[14]; const float* ln0b = (const float*)d_in[15];
    const float* q1W = (const float*)d_in[16]; const float* q1b = (const float*)d_in[17];
    const float* k1W = (const float*)d_in[18]; const float* k1b = (const float*)d_in[19];
    const float* v1W = (const float*)d_in[20]; const float* v1b = (const float*)d_in[21];
    const float* r1W = (const float*)d_in[22]; const float* r1b = (const float*)d_in[23];
    const float* g1W = (const float*)d_in[24];

    const int N = in_sizes[0] / 256;   // 100000
    const int E = in_sizes[1];         // 1600000
    (void)ws_size; (void)n_in; (void)out_size;

    // ---- workspace layout with reuse: peak ~186 MB ----
    auto rnd = [](size_t b) { return (b + 255) & ~(size_t)255; };
    char* base = (char*)d_ws;
    const size_t S_bf = rnd((size_t)N * 128 * 2);   // 25.6 MB
    const size_t S_f  = rnd((size_t)N * 128 * 4);   // 51.2 MB
    size_t o = 0;
    int* row_off = (int*)(base + o); o += rnd(((size_t)N + 1) * 4);
    int* csr     = (int*)(base + o); o += rnd((size_t)E * 4);
    u16* warena  = (u16*)(base + o); o += rnd((size_t)303104 * 2);
    float* barena = (float*)(base + o); o += rnd((size_t)1920 * 4);
    const size_t R0 = o;                 // 51.2: cnt/cur/bsum -> h -> a0 -> {res1o, a1}
    const size_t R1 = R0 + S_f;          // 76.8: x_bf -> QKV0 -> h1 (+ PASS tail)
    const size_t R2 = R1 + 3 * S_bf;     // 51.2: res0o -> (PASS tail)
    int* cnt  = (int*)(base + R0);
    int* cur  = (int*)(base + R0 + rnd((size_t)N * 4));
    int* bsum = (int*)(base + R0 + 2 * rnd((size_t)N * 4));
    u16*   h     = (u16*)(base + R0);
    float* a0    = (float*)(base + R0);
    float* res1o = (float*)(base + R0);
    float* a1    = (float*)(base + R0 + rnd((size_t)N * 64 * 4));
    u16* x_bf = (u16*)(base + R1);                 // N x 256 bf16, dies after in-GEMM
    u16* QKV0 = (u16*)(base + R1);                 // N x 384 bf16 (overlays x_bf)
    u16* h1   = (u16*)(base + R1);                 // N x 128 bf16 (overlays QKV0, dead after attn0)
    u16* PASS = (u16*)(base + R1 + S_bf);          // N x 384 bf16, spans R1 slots 1-2 + R2 head
    float* res0o = (float*)(base + R2);            // dead after gres0 (before PASS written)

    // weight arena sections
    u16* inWt  = warena;
    u16* qkv0t = warena + 32768;
    u16* r0t   = warena + 81920;
    u16* qkv1t = warena + 98304;
    u16* r1t   = warena + 294912;
    float* qkv0b = barena;
    float* qkv1b = barena + 384;

    dim3 blk(256);
    int nwb = (N * 64 + 255) / 256;   // one wave per node
    int nb  = (N + 255) / 256;        // 391 (<= 512)
    int mb  = (N + 127) / 128;        // 782

    // ---- prep (weights/bias/x convert) ----
    prep_k<<<(303104 + 255) / 256, blk, 0, stream>>>(in_W, q0W, k0W, v0W, r0W,
                                                     q1W, k1W, v1W, r1W, warena);
    bias_k<<<8, blk, 0, stream>>>(q0b, k0b, v0b, q1b, k1b, v1b, barena);
    cvt_k<<<(N * 32 + 255) / 256, blk, 0, stream>>>(x, x_bf, N * 32);

    // ---- CSR build ----
    zero2_k<<<nb, blk, 0, stream>>>(cnt, cur, N);
    hist_k<<<(E + 255) / 256, blk, 0, stream>>>(dst, cnt, E);
    blocksum_k<<<nb, blk, 0, stream>>>(cnt, bsum, N);
    scanb_k<<<1, 512, 0, stream>>>(bsum, nb);
    scanc_k<<<nb, blk, 0, stream>>>(cnt, bsum, row_off, N, E);
    scatter_k<<<(E + 255) / 256, blk, 0, stream>>>(src, dst, row_off, cur, csr, E);

    // ---- layer 0 ----
    mgemm4<true, 256, 128><<<mb, blk, 0, stream>>>(x_bf, inWt, in_b, h, N, 128);
    mgemm4<true, 128, 384><<<mb, blk, 0, stream>>>(h, qkv0t, qkv0b, QKV0, N, 384);
    mgemm4<false, 128, 128><<<mb, blk, 0, stream>>>(h, r0t, r0b, res0o, N, 128);

    attn0_k<<<nwb, blk, 0, stream>>>(QKV0, row_off, csr, a0, N);
    gres0_k<<<nwb, blk, 0, stream>>>(a0, res0o, g0W, ln0g, ln0b, h1, N);

    // ---- layer 1: res path, then 4 passes of 2 heads each ----
    mgemm3<false, 128><<<dim3(mb, 1), blk, 0, stream>>>(h1, r1t, r1b, res1o, N, 64, 64);

    for (int p = 0; p < 4; ++p) {
        mgemm4<true, 128, 384><<<mb, blk, 0, stream>>>(
            h1, qkv1t + (size_t)p * 384 * 128, qkv1b + p * 384, PASS, N, 384);
        if (p == 0) attn1_k<true><<<nwb, blk, 0, stream>>>(PASS, row_off, csr, a1, N);
        else        attn1_k<false><<<nwb, blk, 0, stream>>>(PASS, row_off, csr, a1, N);
    }

    gres1_k<<<nwb, blk, 0, stream>>>(a1, res1o, g1W, (float*)d_out, N);
}

// Round 8
// 1241.558 us; speedup vs baseline: 1.1715x; 1.1715x over previous
//
#include <hip/hip_runtime.h>

// GraphTransformerModel: 2-layer graph attention network.
// CSR build -> bf16 MFMA GEMMs (mgemm5: A staged once, B-tiles iterated; 64KB LDS)
// -> attn0 -> gres0+LN -> 4x {qkv1 GEMM -> attn1} -> gres1.
// q/k/v live in fused [N][384] bf16 buffers; all accumulation f32.
// Peak workspace ~186 MB.

typedef unsigned short u16;
typedef __attribute__((ext_vector_type(8))) unsigned short ushort8;
typedef __attribute__((ext_vector_type(8))) short short8v;   // 8 bf16 (4 VGPRs)
typedef __attribute__((ext_vector_type(4))) float f32x4;

__device__ __forceinline__ float bf2f(unsigned short u) {
    return __uint_as_float(((unsigned)u) << 16);
}
__device__ __forceinline__ unsigned short f2bf(float f) {
    unsigned u = __float_as_uint(f);
    unsigned r = 0x7fffu + ((u >> 16) & 1u);   // round-to-nearest-even
    return (unsigned short)((u + r) >> 16);
}

// async global->LDS, 16B per lane; dest is wave-uniform base + lane*16 (HW).
__device__ __forceinline__ void gload16(const void* gp, const void* lp) {
    __builtin_amdgcn_global_load_lds(
        (const __attribute__((address_space(1))) unsigned*)(uintptr_t)gp,
        (__attribute__((address_space(3))) unsigned*)(unsigned)(uintptr_t)lp,
        16, 0, 0);
}

// ---------------- fused weight prep: all transposed bf16 weights in one kernel ----------------
// arena (u16): [0)=inWt[128][256]  [32768)=qkv0t[384][128]  [81920)=r0t[128][128]
//              [98304)=qkv1t[4][384][128]  [294912)=r1t[64][128]  total 303104
__global__ void prep_k(const float* __restrict__ inW,
                       const float* __restrict__ q0W, const float* __restrict__ k0W,
                       const float* __restrict__ v0W, const float* __restrict__ r0W,
                       const float* __restrict__ q1W, const float* __restrict__ k1W,
                       const float* __restrict__ v1W, const float* __restrict__ r1W,
                       u16* __restrict__ arena) {
    int i = blockIdx.x * 256 + threadIdx.x;
    if (i >= 303104) return;
    float val;
    if (i < 32768) {                       // inWt[n][k] = inW[k][n], K=256, N=128
        int n = i >> 8, k = i & 255;
        val = inW[k * 128 + n];
    } else if (i < 81920) {                // qkv0t
        int j = i - 32768;
        int r = j >> 7, kk = j & 127;
        int sec = r >> 7, c = r & 127;
        const float* s = (sec == 0) ? q0W : (sec == 1) ? k0W : v0W;
        val = s[kk * 128 + c];
    } else if (i < 98304) {                // r0t
        int j = i - 81920;
        int r = j >> 7, kk = j & 127;
        val = r0W[kk * 128 + r];
    } else if (i < 294912) {               // qkv1t[p][384][128]
        int j = i - 98304;
        int row = j >> 7, kk = j & 127;
        int p = row / 384, rr = row - p * 384;
        int sec = rr >> 7, c = p * 128 + (rr & 127);
        const float* s = (sec == 0) ? q1W : (sec == 1) ? k1W : v1W;
        val = s[kk * 512 + c];
    } else {                               // r1t[64][128]
        int j = i - 294912;
        int n = j >> 7, kk = j & 127;
        val = r1W[kk * 64 + n];
    }
    arena[i] = f2bf(val);
}

// fused biases: qkv0b[384] then qkv1b[4*384]
__global__ void bias_k(const float* __restrict__ q0b, const float* __restrict__ k0b,
                       const float* __restrict__ v0b,
                       const float* __restrict__ q1b, const float* __restrict__ k1b,
                       const float* __restrict__ v1b, float* __restrict__ out) {
    int i = blockIdx.x * 256 + threadIdx.x;
    if (i >= 1920) return;
    if (i < 384) {
        int sec = i >> 7, c = i & 127;
        out[i] = (sec == 0) ? q0b[c] : (sec == 1) ? k0b[c] : v0b[c];
    } else {
        int j = i - 384;
        int p = j / 384, rr = j - p * 384;
        int sec = rr >> 7, c = p * 128 + (rr & 127);
        out[i] = (sec == 0) ? q1b[c] : (sec == 1) ? k1b[c] : v1b[c];
    }
}

// ---------------- f32 -> bf16 convert (8 elems/thread) ----------------
__global__ void cvt_k(const float* __restrict__ in, u16* __restrict__ out, int n8) {
    int i = blockIdx.x * 256 + threadIdx.x;
    if (i >= n8) return;
    float4 a = *(const float4*)(in + (size_t)i * 8);
    float4 b = *(const float4*)(in + (size_t)i * 8 + 4);
    ushort8 o = {f2bf(a.x), f2bf(a.y), f2bf(a.z), f2bf(a.w),
                 f2bf(b.x), f2bf(b.y), f2bf(b.z), f2bf(b.w)};
    *(ushort8*)(out + (size_t)i * 8) = o;
}

// ---------------- MFMA GEMM v5: K=128, N = NT*128. A staged ONCE, B-tiles iterated.
// LDS = 32KB A + 32KB B -> 2 blocks/CU. XOR-swizzled (pre-swizzled source, XOR read).
// 256 thr = 4 waves (2x2 of 64x64). Accumulation order identical to mgemm3.
template <bool OUTBF16, int NT>
__global__ __launch_bounds__(256) void mgemm5(const u16* __restrict__ A,
                                              const u16* __restrict__ Bt,
                                              const float* __restrict__ bias,
                                              void* __restrict__ C, int M, int ldc) {
    __shared__ __align__(16) u16 As[128 * 128];   // 32 KB, 256B rows
    __shared__ __align__(16) u16 Bs[128 * 128];   // 32 KB
    const int bm = blockIdx.x * 128;
    const int t = threadIdx.x, lane = t & 63, wid = t >> 6;
    const int wm = (wid >> 1) * 64, wn = (wid & 1) * 64;
    const int lrow = lane >> 4, lchunk = lane & 15;   // 16 chunks/row, 4 rows/KB-seg
    // ---- stage full-K A tile once ----
#pragma unroll
    for (int sg = 0; sg < 32; sg += 4) {
        int seg = sg + wid;                        // wave-uniform
        int row = seg * 4 + lrow;
        int lc = (lchunk ^ (row & 7)) * 8;         // pre-swizzled source col
        int gr = bm + row; if (gr >= M) gr = 0;    // clamped; epilogue guards
        gload16(A + (size_t)gr * 128 + lc, (const char*)As + seg * 1024);
    }
#pragma unroll
    for (int nit = 0; nit < NT; ++nit) {
        if (nit) __syncthreads();                  // all waves done reading prev Bs
#pragma unroll
        for (int sg = 0; sg < 32; sg += 4) {
            int seg = sg + wid;
            int row = seg * 4 + lrow;
            int lc = (lchunk ^ (row & 7)) * 8;
            gload16(Bt + (size_t)(nit * 128 + row) * 128 + lc, (const char*)Bs + seg * 1024);
        }
        __syncthreads();                           // drains vmcnt: A (first iter) + B landed
        f32x4 acc[4][4] = {};
#pragma unroll
        for (int ks = 0; ks < 4; ++ks) {
            const int jx = ks * 4 + (lane >> 4);   // logical 16B chunk index
            short8v af[4], bfr[4];
#pragma unroll
            for (int i = 0; i < 4; ++i) {
                int ra = wm + i * 16 + (lane & 15);
                af[i] = *(const short8v*)((const char*)As + ra * 256 + ((jx ^ (ra & 7)) << 4));
                int rb = wn + i * 16 + (lane & 15);
                bfr[i] = *(const short8v*)((const char*)Bs + rb * 256 + ((jx ^ (rb & 7)) << 4));
            }
#pragma unroll
            for (int mi = 0; mi < 4; ++mi)
#pragma unroll
                for (int ni = 0; ni < 4; ++ni)
                    acc[mi][ni] = __builtin_amdgcn_mfma_f32_16x16x32_bf16(
                        af[mi], bfr[ni], acc[mi][ni], 0, 0, 0);
        }
        // epilogue: C/D frag layout col=lane&15, row=(lane>>4)*4+j
#pragma unroll
        for (int ni = 0; ni < 4; ++ni) {
            int ccol = nit * 128 + wn + ni * 16 + (lane & 15);
            float bs = bias[ccol];
#pragma unroll
            for (int mi = 0; mi < 4; ++mi) {
#pragma unroll
                for (int j = 0; j < 4; ++j) {
                    int crow = bm + wm + mi * 16 + (lane >> 4) * 4 + j;
                    if (crow >= M) continue;
                    float val = acc[mi][ni][j] + bs;
                    if (OUTBF16) ((u16*)C)[(size_t)crow * ldc + ccol] = f2bf(val);
                    else         ((float*)C)[(size_t)crow * ldc + ccol] = val;
                }
            }
        }
    }
}

// ---------------- MFMA GEMM v3 (in/r0/r1): 128x128 tiles, BK=64 chunks ----------
template <bool OUTBF16, int K>
__global__ __launch_bounds__(256) void mgemm3(const u16* __restrict__ A,
                                              const u16* __restrict__ Bt,
                                              const float* __restrict__ bias,
                                              void* __restrict__ C,
                                              int M, int Nvalid, int ldc) {
    __shared__ __align__(16) u16 As[128 * 64];
    __shared__ __align__(16) u16 Bs[128 * 64];
    const int bm = blockIdx.x * 128;
    const int bn = blockIdx.y * 128;
    const int t = threadIdx.x, lane = t & 63, wid = t >> 6;
    const int wm = (wid >> 1) * 64, wn = (wid & 1) * 64;
    const int jlog = ((lane & 7) ^ (lane >> 3)) * 8;
    f32x4 acc[4][4] = {};
    for (int k0 = 0; k0 < K; k0 += 64) {
#pragma unroll
        for (int c2 = 0; c2 < 4; ++c2) {
            int seg = c2 * 4 + wid;
            int row = seg * 8 + (lane >> 3);
            int ga = bm + row; if (ga >= M) ga = 0;
            gload16(A + (size_t)ga * K + k0 + jlog, (const char*)As + seg * 1024);
            int gb = bn + row; if (gb >= Nvalid) gb = 0;
            gload16(Bt + (size_t)gb * K + k0 + jlog, (const char*)Bs + seg * 1024);
        }
        __syncthreads();
#pragma unroll
        for (int ks = 0; ks < 2; ++ks) {
            const int jx = ks * 4 + (lane >> 4);
            short8v af[4], bfr[4];
#pragma unroll
            for (int i = 0; i < 4; ++i) {
                int ra = wm + i * 16 + (lane & 15);
                af[i] = *(const short8v*)((const char*)As + ra * 128 + ((jx ^ (ra & 7)) << 4));
                int rb = wn + i * 16 + (lane & 15);
                bfr[i] = *(const short8v*)((const char*)Bs + rb * 128 + ((jx ^ (rb & 7)) << 4));
            }
#pragma unroll
            for (int mi = 0; mi < 4; ++mi)
#pragma unroll
                for (int ni = 0; ni < 4; ++ni)
                    acc[mi][ni] = __builtin_amdgcn_mfma_f32_16x16x32_bf16(
                        af[mi], bfr[ni], acc[mi][ni], 0, 0, 0);
        }
        if (k0 + 64 < K) __syncthreads();
    }
#pragma unroll
    for (int ni = 0; ni < 4; ++ni) {
        int ccol = bn + wn + ni * 16 + (lane & 15);
        if (ccol >= Nvalid) continue;
        float bs = bias[ccol];
#pragma unroll
        for (int mi = 0; mi < 4; ++mi) {
#pragma unroll
            for (int j = 0; j < 4; ++j) {
                int crow = bm + wm + mi * 16 + (lane >> 4) * 4 + j;
                if (crow >= M) continue;
                float val = acc[mi][ni][j] + bs;
                if (OUTBF16) ((u16*)C)[(size_t)crow * ldc + ccol] = f2bf(val);
                else         ((float*)C)[(size_t)crow * ldc + ccol] = val;
            }
        }
    }
}

// ---------------- CSR build ----------------
__global__ void zero2_k(int* __restrict__ a, int* __restrict__ b, int n) {
    int i = blockIdx.x * 256 + threadIdx.x;
    if (i < n) { a[i] = 0; b[i] = 0; }
}

__global__ void hist_k(const int* __restrict__ dst, int* __restrict__ cnt, int E) {
    int i = blockIdx.x * 256 + threadIdx.x;
    if (i < E) atomicAdd(&cnt[dst[i]], 1);
}

__global__ void blocksum_k(const int* __restrict__ cnt, int* __restrict__ bsum, int n) {
    __shared__ int sd[256];
    int i = blockIdx.x * 256 + threadIdx.x;
    sd[threadIdx.x] = (i < n) ? cnt[i] : 0;
    __syncthreads();
    for (int off = 128; off > 0; off >>= 1) {
        if (threadIdx.x < off) sd[threadIdx.x] += sd[threadIdx.x + off];
        __syncthreads();
    }
    if (threadIdx.x == 0) bsum[blockIdx.x] = sd[0];
}

__global__ void scanb_k(int* bsum, int nb) {
    __shared__ int tmp[512];
    int t = threadIdx.x;
    tmp[t] = (t < nb) ? bsum[t] : 0;
    __syncthreads();
    for (int off = 1; off < 512; off <<= 1) {
        int v = (t >= off) ? tmp[t - off] : 0;
        __syncthreads();
        tmp[t] += v;
        __syncthreads();
    }
    if (t < nb) bsum[t] = (t ? tmp[t - 1] : 0);
}

__global__ void scanc_k(const int* __restrict__ cnt, const int* __restrict__ bsum,
                        int* __restrict__ row_off, int n, int E) {
    __shared__ int tmp[256];
    int b = blockIdx.x, t = threadIdx.x;
    int i = b * 256 + t;
    int own = (i < n) ? cnt[i] : 0;
    tmp[t] = own;
    __syncthreads();
    for (int off = 1; off < 256; off <<= 1) {
        int v = (t >= off) ? tmp[t - off] : 0;
        __syncthreads();
        tmp[t] += v;
        __syncthreads();
    }
    if (i < n) row_off[i] = bsum[b] + tmp[t] - own;
    if (b == 0 && t == 0) row_off[n] = E;
}

__global__ void scatter_k(const int* __restrict__ src, const int* __restrict__ dst,
                          const int* __restrict__ row_off, int* __restrict__ cur,
                          int* __restrict__ csr_src, int E) {
    int i = blockIdx.x * 256 + threadIdx.x;
    if (i < E) {
        int d = dst[i];
        int pos = row_off[d] + atomicAdd(&cur[d], 1);
        csr_src[pos] = src[i];
    }
}

// ---------------- attention layer 0: 8 heads x d=16, F=128, concat ----------------
// q/k/v at row stride 384 (fused buffer). lane l: feats 2l,2l+1; 8-lane reduce. Unroll 4.
__global__ __launch_bounds__(256) void attn0_k(const u16* __restrict__ q, const u16* __restrict__ k,
                                               const u16* __restrict__ v,
                                               const int* __restrict__ row_off,
                                               const int* __restrict__ csr,
                                               float* __restrict__ out, int n) {
    int w = (blockIdx.x * 256 + threadIdx.x) >> 6;
    int lane = threadIdx.x & 63;
    if (w >= n) return;
    int beg = row_off[w], end = row_off[w + 1];
    unsigned kv = *(const unsigned*)(k + (size_t)w * 384 + 2 * lane);
    float k0f = bf2f((u16)kv) * 0.25f, k1f = bf2f((u16)(kv >> 16)) * 0.25f;  // fold 1/sqrt(16)
    float den = 0.f, num0 = 0.f, num1 = 0.f;
    int e = beg;
    for (; e + 4 <= end; e += 4) {
        int s0 = csr[e], s1 = csr[e + 1], s2 = csr[e + 2], s3 = csr[e + 3];
        unsigned qa = *(const unsigned*)(q + (size_t)s0 * 384 + 2 * lane);
        unsigned qb = *(const unsigned*)(q + (size_t)s1 * 384 + 2 * lane);
        unsigned qc = *(const unsigned*)(q + (size_t)s2 * 384 + 2 * lane);
        unsigned qd = *(const unsigned*)(q + (size_t)s3 * 384 + 2 * lane);
        unsigned va = *(const unsigned*)(v + (size_t)s0 * 384 + 2 * lane);
        unsigned vb = *(const unsigned*)(v + (size_t)s1 * 384 + 2 * lane);
        unsigned vc = *(const unsigned*)(v + (size_t)s2 * 384 + 2 * lane);
        unsigned vd = *(const unsigned*)(v + (size_t)s3 * 384 + 2 * lane);
        float pa = bf2f((u16)qa) * k0f + bf2f((u16)(qa >> 16)) * k1f;
        float pb = bf2f((u16)qb) * k0f + bf2f((u16)(qb >> 16)) * k1f;
        float pc = bf2f((u16)qc) * k0f + bf2f((u16)(qc >> 16)) * k1f;
        float pd = bf2f((u16)qd) * k0f + bf2f((u16)(qd >> 16)) * k1f;
#pragma unroll
        for (int off = 1; off < 8; off <<= 1) {
            pa += __shfl_xor(pa, off); pb += __shfl_xor(pb, off);
            pc += __shfl_xor(pc, off); pd += __shfl_xor(pd, off);
        }
        float wa = __expf(pa), wb = __expf(pb);
        float wc = __expf(pc), wd = __expf(pd);
        den += (wa + wb) + (wc + wd);
        num0 = fmaf(wa, bf2f((u16)va), num0);
        num1 = fmaf(wa, bf2f((u16)(va >> 16)), num1);
        num0 = fmaf(wb, bf2f((u16)vb), num0);
        num1 = fmaf(wb, bf2f((u16)(vb >> 16)), num1);
        num0 = fmaf(wc, bf2f((u16)vc), num0);
        num1 = fmaf(wc, bf2f((u16)(vc >> 16)), num1);
        num0 = fmaf(wd, bf2f((u16)vd), num0);
        num1 = fmaf(wd, bf2f((u16)(vd >> 16)), num1);
    }
    for (; e < end; ++e) {
        int s = csr[e];
        unsigned qv = *(const unsigned*)(q + (size_t)s * 384 + 2 * lane);
        float p = bf2f((u16)qv) * k0f + bf2f((u16)(qv >> 16)) * k1f;
        p += __shfl_xor(p, 1);
        p += __shfl_xor(p, 2);
        p += __shfl_xor(p, 4);
        float wt = __expf(p);
        den += wt;
        unsigned vv = *(const unsigned*)(v + (size_t)s * 384 + 2 * lane);
        num0 = fmaf(wt, bf2f((u16)vv), num0);
        num1 = fmaf(wt, bf2f((u16)(vv >> 16)), num1);
    }
    float inv = (end > beg) ? 1.f / den : 0.f;
    *(float2*)(out + ((size_t)w << 7) + 2 * lane) = make_float2(num0 * inv, num1 * inv);
}

// ---------------- attention layer 1 (one 2-head pass): d=64, accumulate mean ----------------
template <bool FIRST>
__global__ __launch_bounds__(256) void attn1_k(const u16* __restrict__ q, const u16* __restrict__ k,
                                               const u16* __restrict__ v,
                                               const int* __restrict__ row_off,
                                               const int* __restrict__ csr,
                                               float* __restrict__ out, int n) {
    int w = (blockIdx.x * 256 + threadIdx.x) >> 6;
    int lane = threadIdx.x & 63;
    if (w >= n) return;
    int beg = row_off[w], end = row_off[w + 1];
    unsigned kv = *(const unsigned*)(k + (size_t)w * 384 + 2 * lane);
    float k0f = bf2f((u16)kv) * 0.125f, k1f = bf2f((u16)(kv >> 16)) * 0.125f;  // fold 1/sqrt(64)
    float den = 0.f, num0 = 0.f, num1 = 0.f;
    int e = beg;
    for (; e + 4 <= end; e += 4) {
        int s0 = csr[e], s1 = csr[e + 1], s2 = csr[e + 2], s3 = csr[e + 3];
        unsigned qa = *(const unsigned*)(q + (size_t)s0 * 384 + 2 * lane);
        unsigned qb = *(const unsigned*)(q + (size_t)s1 * 384 + 2 * lane);
        unsigned qc = *(const unsigned*)(q + (size_t)s2 * 384 + 2 * lane);
        unsigned qd = *(const unsigned*)(q + (size_t)s3 * 384 + 2 * lane);
        unsigned va = *(const unsigned*)(v + (size_t)s0 * 384 + 2 * lane);
        unsigned vb = *(const unsigned*)(v + (size_t)s1 * 384 + 2 * lane);
        unsigned vc = *(const unsigned*)(v + (size_t)s2 * 384 + 2 * lane);
        unsigned vd = *(const unsigned*)(v + (size_t)s3 * 384 + 2 * lane);
        float pa = bf2f((u16)qa) * k0f + bf2f((u16)(qa >> 16)) * k1f;
        float pb = bf2f((u16)qb) * k0f + bf2f((u16)(qb >> 16)) * k1f;
        float pc = bf2f((u16)qc) * k0f + bf2f((u16)(qc >> 16)) * k1f;
        float pd = bf2f((u16)qd) * k0f + bf2f((u16)(qd >> 16)) * k1f;
#pragma unroll
        for (int off = 1; off < 32; off <<= 1) {
            pa += __shfl_xor(pa, off); pb += __shfl_xor(pb, off);
            pc += __shfl_xor(pc, off); pd += __shfl_xor(pd, off);
        }
        float wa = __expf(pa), wb = __expf(pb);
        float wc = __expf(pc), wd = __expf(pd);
        den += (wa + wb) + (wc + wd);
        num0 = fmaf(wa, bf2f((u16)va), num0);
        num1 = fmaf(wa, bf2f((u16)(va >> 16)), num1);
        num0 = fmaf(wb, bf2f((u16)vb), num0);
        num1 = fmaf(wb, bf2f((u16)(vb >> 16)), num1);
        num0 = fmaf(wc, bf2f((u16)vc), num0);
        num1 = fmaf(wc, bf2f((u16)(vc >> 16)), num1);
        num0 = fmaf(wd, bf2f((u16)vd), num0);
        num1 = fmaf(wd, bf2f((u16)(vd >> 16)), num1);
    }
    for (; e < end; ++e) {
        int s = csr[e];
        unsigned qv = *(const unsigned*)(q + (size_t)s * 384 + 2 * lane);
        float p = bf2f((u16)qv) * k0f + bf2f((u16)(qv >> 16)) * k1f;
#pragma unroll
        for (int off = 1; off < 32; off <<= 1) p += __shfl_xor(p, off);
        float wt = __expf(p);
        den += wt;
        unsigned vv = *(const unsigned*)(v + (size_t)s * 384 + 2 * lane);
        num0 = fmaf(wt, bf2f((u16)vv), num0);
        num1 = fmaf(wt, bf2f((u16)(vv >> 16)), num1);
    }
    float inv = (end > beg) ? 1.f / den : 0.f;
    float o0 = num0 * inv, o1 = num1 * inv;
    o0 += __shfl_xor(o0, 32);   // combine the two heads (same output dim)
    o1 += __shfl_xor(o1, 32);
    if (lane < 32) {
        float2* op = (float2*)(out + ((size_t)w << 6) + 2 * lane);
        if (FIRST) {
            *op = make_float2(o0 * 0.125f, o1 * 0.125f);
        } else {
            float2 tv = *op;
            tv.x += o0 * 0.125f; tv.y += o1 * 0.125f;
            *op = tv;
        }
    }
}

// ---------------- gated residual + LN + relu (layer 0), bf16 h1 out ----------------
__global__ __launch_bounds__(256) void gres0_k(const float* __restrict__ x, const float* __restrict__ res,
                                               const float* __restrict__ gw,
                                               const float* __restrict__ lng, const float* __restrict__ lnb,
                                               u16* __restrict__ h1, int n) {
    int w = (blockIdx.x * 256 + threadIdx.x) >> 6;
    int lane = threadIdx.x & 63;
    if (w >= n) return;
    size_t base = (size_t)w * 128;
    float x1 = x[base + lane], x2 = x[base + lane + 64];
    float r1 = res[base + lane], r2 = res[base + lane + 64];
    float ca1 = gw[lane] + gw[256 + lane];
    float ca2 = gw[lane + 64] + gw[256 + lane + 64];
    float cr1 = gw[128 + lane] - gw[256 + lane];
    float cr2 = gw[128 + lane + 64] - gw[256 + lane + 64];
    float dot = x1 * ca1 + x2 * ca2 + r1 * cr1 + r2 * cr2;
#pragma unroll
    for (int off = 1; off < 64; off <<= 1) dot += __shfl_xor(dot, off);
    float g = 1.f / (1.f + __expf(-dot));
    float o1 = x1 * g + r1 * (1.f - g);
    float o2 = x2 * g + r2 * (1.f - g);
    float s = o1 + o2;
#pragma unroll
    for (int off = 1; off < 64; off <<= 1) s += __shfl_xor(s, off);
    float mu = s * (1.f / 128.f);
    float d1 = o1 - mu, d2 = o2 - mu;
    float vs = d1 * d1 + d2 * d2;
#pragma unroll
    for (int off = 1; off < 64; off <<= 1) vs += __shfl_xor(vs, off);
    float rstd = rsqrtf(vs * (1.f / 128.f) + 1e-5f);
    float y1 = d1 * rstd * lng[lane] + lnb[lane];
    float y2 = d2 * rstd * lng[lane + 64] + lnb[lane + 64];
    h1[base + lane] = f2bf(fmaxf(y1, 0.f));
    h1[base + lane + 64] = f2bf(fmaxf(y2, 0.f));
}

// ---------------- gated residual only (layer 1, d=64) ----------------
__global__ __launch_bounds__(256) void gres1_k(const float* __restrict__ x, const float* __restrict__ res,
                                               const float* __restrict__ gw,
                                               float* __restrict__ out, int n) {
    int w = (blockIdx.x * 256 + threadIdx.x) >> 6;
    int lane = threadIdx.x & 63;
    if (w >= n) return;
    size_t base = (size_t)w * 64;
    float xv = x[base + lane];
    float rv = res[base + lane];
    float ca = gw[lane] + gw[128 + lane];
    float cr = gw[64 + lane] - gw[128 + lane];
    float dot = xv * ca + rv * cr;
#pragma unroll
    for (int off = 1; off < 64; off <<= 1) dot += __shfl_xor(dot, off);
    float g = 1.f / (1.f + __expf(-dot));
    out[base + lane] = xv * g + rv * (1.f - g);
}

extern "C" void kernel_launch(void* const* d_in, const int* in_sizes, int n_in,
                              void* d_out, int out_size, void* d_ws, size_t ws_size,
                              hipStream_t stream) {
    const float* x    = (const float*)d_in[0];
    const int*   src  = (const int*)d_in[1];
    const int*   dst  = (const int*)d_in[2];
    const float* in_W = (const float*)d_in[3];
    const float* in_b = (const float*)d_in[4];
    const float* q0W = (const float*)d_in[5];  const float* q0b = (const float*)d_in[6];
    const float* k0W = (const float*)d_in[7];  const float* k0b = (const float*)d_in[8];
    const float* v0W = (const float*)d_in[9];  const float* v0b = (const float*)d_in[10];
    const float* r0W = (const float*)d_in[11]; const float* r0b = (const float*)d_in[12];
    const float* g0W = (const float*)d_in[13];
    const float* ln0g = (const float*)d_in[14]; const float* ln0b = (const float*)d_in[15];
    const float* q1W = (const float*)d_in[16]; const float* q1b = (const float*)d_in[17];
    const float* k1W = (const float*)d_in[18]; const float* k1b = (const float*)d_in[19];
    const float* v1W = (const float*)d_in[20]; const float* v1b = (const float*)d_in[21];
    const float* r1W = (const float*)d_in[22]; const float* r1b = (const float*)d_in[23];
    const float* g1W = (const float*)d_in[24];

    const int N = in_sizes[0] / 256;   // 100000
    const int E = in_sizes[1];         // 1600000
    (void)ws_size; (void)n_in; (void)out_size;

    // ---- workspace layout with reuse: peak ~186 MB ----
    auto rnd = [](size_t b) { return (b + 255) & ~(size_t)255; };
    char* base = (char*)d_ws;
    const size_t S_bf = rnd((size_t)N * 128 * 2);   // 25.6 MB
    const size_t S_f  = rnd((size_t)N * 128 * 4);   // 51.2 MB
    size_t o = 0;
    int* row_off = (int*)(base + o); o += rnd(((size_t)N + 1) * 4);
    int* csr     = (int*)(base + o); o += rnd((size_t)E * 4);
    u16* warena  = (u16*)(base + o); o += rnd((size_t)303104 * 2);
    float* barena = (float*)(base + o); o += rnd((size_t)1920 * 4);
    const size_t R0 = o;                 // 51.2: cnt/cur/bsum -> h -> a0 -> {res1o, a1}
    const size_t R1 = R0 + S_f;          // 76.8: x_bf -> QKV0 -> h1 (+ PASS tail)
    const size_t R2 = R1 + 3 * S_bf;     // 51.2: res0o -> (PASS tail)
    int* cnt  = (int*)(base + R0);
    int* cur  = (int*)(base + R0 + rnd((size_t)N * 4));
    int* bsum = (int*)(base + R0 + 2 * rnd((size_t)N * 4));
    u16*   h     = (u16*)(base + R0);
    float* a0    = (float*)(base + R0);
    float* res1o = (float*)(base + R0);
    float* a1    = (float*)(base + R0 + rnd((size_t)N * 64 * 4));
    u16* x_bf = (u16*)(base + R1);                 // N x 256 bf16, dies after in-GEMM
    u16* QKV0 = (u16*)(base + R1);                 // N x 384 bf16 (overlays x_bf)
    u16* h1   = (u16*)(base + R1);                 // N x 128 bf16 (overlays QKV0, dead after attn0)
    u16* PASS = (u16*)(base + R1 + S_bf);          // N x 384 bf16, spans R1 slots 1-2 + R2 head
    float* res0o = (float*)(base + R2);            // dead after gres0 (before PASS written)

    // weight arena sections
    u16* inWt  = warena;
    u16* qkv0t = warena + 32768;
    u16* r0t   = warena + 81920;
    u16* qkv1t = warena + 98304;
    u16* r1t   = warena + 294912;
    float* qkv0b = barena;
    float* qkv1b = barena + 384;

    dim3 blk(256);
    int nwb = (N * 64 + 255) / 256;   // one wave per node
    int nb  = (N + 255) / 256;        // 391 (<= 512)
    int mb  = (N + 127) / 128;        // 782

    // ---- prep (weights/bias/x convert) ----
    prep_k<<<(303104 + 255) / 256, blk, 0, stream>>>(in_W, q0W, k0W, v0W, r0W,
                                                     q1W, k1W, v1W, r1W, warena);
    bias_k<<<8, blk, 0, stream>>>(q0b, k0b, v0b, q1b, k1b, v1b, barena);
    cvt_k<<<(N * 32 + 255) / 256, blk, 0, stream>>>(x, x_bf, N * 32);

    // ---- CSR build ----
    zero2_k<<<nb, blk, 0, stream>>>(cnt, cur, N);
    hist_k<<<(E + 255) / 256, blk, 0, stream>>>(dst, cnt, E);
    blocksum_k<<<nb, blk, 0, stream>>>(cnt, bsum, N);
    scanb_k<<<1, 512, 0, stream>>>(bsum, nb);
    scanc_k<<<nb, blk, 0, stream>>>(cnt, bsum, row_off, N, E);
    scatter_k<<<(E + 255) / 256, blk, 0, stream>>>(src, dst, row_off, cur, csr, E);

    // ---- layer 0 ----
    mgemm3<true, 256><<<dim3(mb, 1), blk, 0, stream>>>(x_bf, inWt, in_b, h, N, 128, 128);
    mgemm5<true, 3><<<mb, blk, 0, stream>>>(h, qkv0t, qkv0b, QKV0, N, 384);
    mgemm3<false, 128><<<dim3(mb, 1), blk, 0, stream>>>(h, r0t, r0b, res0o, N, 128, 128);

    attn0_k<<<nwb, blk, 0, stream>>>(QKV0, QKV0 + 128, QKV0 + 256, row_off, csr, a0, N);
    gres0_k<<<nwb, blk, 0, stream>>>(a0, res0o, g0W, ln0g, ln0b, h1, N);

    // ---- layer 1: res path, then 4 passes of 2 heads each ----
    mgemm3<false, 128><<<dim3(mb, 1), blk, 0, stream>>>(h1, r1t, r1b, res1o, N, 64, 64);

    for (int p = 0; p < 4; ++p) {
        mgemm5<true, 3><<<mb, blk, 0, stream>>>(
            h1, qkv1t + (size_t)p * 384 * 128, qkv1b + p * 384, PASS, N, 384);
        if (p == 0) attn1_k<true><<<nwb, blk, 0, stream>>>(PASS, PASS + 128, PASS + 256,
                                                           row_off, csr, a1, N);
        else        attn1_k<false><<<nwb, blk, 0, stream>>>(PASS, PASS + 128, PASS + 256,
                                                            row_off, csr, a1, N);
    }

    gres1_k<<<nwb, blk, 0, stream>>>(a1, res1o, g1W, (float*)d_out, N);
}